// Round 6
// baseline (198.789 us; speedup 1.0000x reference)
//
#include <hip/hip_runtime.h>

// PS_L20_LSTM — 32x32x16 MFMA, register-resident h (no h LDS round-trip).
// Gate GEMM D = Wih·feat^T with K=16 (15 feats + fused-bias column, feat[15]=1).
// D rows = neurons -> activations in regs -> shfl_xor(32) half-swap builds the
// head B-frags directly. Head GEMM D2 = W1·h^T, K=128 in 8 ksteps.
// All weight frags pre-staged in LDS in frag-order (lane-contiguous b128).
// Wave-independent 32-row tiles; one barrier total (weight staging).

typedef _Float16 half8v   __attribute__((ext_vector_type(8)));
typedef _Float16 half4v   __attribute__((ext_vector_type(4)));
typedef float    float16v __attribute__((ext_vector_type(16)));

#define N_SZ   2048
#define ROWS   262144
#define BLOCKT 256
#define NBLK   512          // 512 blk x 4 waves x 4 iters x 32 rows = 262144
#define WITERS 4
#define WROWS  32

union H4 { half4v h; unsigned int u[2]; };
union B8 { half8v h; unsigned int u[4]; };

__device__ __forceinline__ float fast_rcp(float x) { return __builtin_amdgcn_rcpf(x); }
__device__ __forceinline__ float sigm(float x)  { return fast_rcp(1.0f + __expf(-x)); }
__device__ __forceinline__ float tanh_f(float x){ return 1.0f - 2.0f * fast_rcp(1.0f + __expf(2.0f * x)); }
// |y| <= 1: odd deg-7 minimax, err ~1e-4, full-rate FMA pipe
__device__ __forceinline__ float tanh_c(float y) {
    const float t = y * y;
    return y * __builtin_fmaf(t, __builtin_fmaf(t, __builtin_fmaf(t,
            -0.02714f, 0.12052f), -0.33157f), 0.99986f);
}

__global__ __launch_bounds__(BLOCKT, 2)
void ps_lstm_r32(const float* __restrict__ x_,
                 const float* __restrict__ x1_,
                 const float* __restrict__ x2_,
                 const float* __restrict__ z1_,
                 const float* __restrict__ z2_,
                 const float* __restrict__ x1E_,
                 const float* __restrict__ x2E_,
                 const float* __restrict__ z1E_,
                 const float* __restrict__ z2E_,
                 const float* __restrict__ muB_,
                 const float* __restrict__ lb_,
                 const float* __restrict__ ub_,
                 const float* __restrict__ Wih_,   // [512][15]
                 const float* __restrict__ bih_,   // [512]
                 const float* __restrict__ bhh_,   // [512]
                 const float* __restrict__ W1_,    // [128][128]
                 const float* __restrict__ b1_,    // [128]
                 const float* __restrict__ W2_,    // [128]
                 const float* __restrict__ b2_,    // [1]
                 float* __restrict__ out_)         // [128][5*2048]
{
    // frag-order: consecutive lanes own consecutive 16B chunks -> conflict-free b128
    __shared__ __align__(16) _Float16 fragWih[3 * 4 * 64 * 8];  // 12 KB [gate][nt][lane][8]
    __shared__ __align__(16) _Float16 fragW1 [4 * 8 * 64 * 8];  // 32 KB [mt2][kstep][lane][8]
    __shared__ __align__(16) _Float16 sFeat[4][WROWS * 16];     // 4 KB  per-wave [row][k]
    __shared__ __align__(16) float sB1[128];
    __shared__ __align__(16) float sW2[128];

    const int tid  = threadIdx.x;
    const int lane = tid & 63;
    const int w    = tid >> 6;
    const int m32  = lane & 31;    // MFMA col lane index (batch row / A-row)
    const int hk   = lane >> 5;    // K-half selector

    // ---------- one-time frag staging ----------
    // Wih A-frags: A[m=neuron][k], k=15 is the fused bias column.
    #pragma unroll
    for (int g = 0; g < 3; ++g) {
        const int chunk = g * 256 + tid;          // ((g*4+nt)*64+l)
        const int l  = tid & 63;
        const int nt = tid >> 6;
        const int m  = nt * 32 + (l & 31);
        const int kh = (l >> 5) & 1;
        const int grow = (g == 0 ? m : (g == 1 ? 256 + m : 384 + m)); // i,g,o (skip f)
        half8v hh;
        #pragma unroll
        for (int j = 0; j < 8; ++j) {
            const int k = kh * 8 + j;
            const float v = (k < 15) ? Wih_[grow * 15 + k]
                                     : (bih_[grow] + bhh_[grow]);
            hh[j] = (_Float16)v;
        }
        *(half8v*)&fragWih[(size_t)chunk * 8] = hh;
    }
    // W1 A-frags: A[m=neuron2][k=kstep*16 + kh*8 + j]
    #pragma unroll
    for (int i = 0; i < 8; ++i) {
        const int chunk = i * 256 + tid;          // ((mt2*8+kstep)*64+l)
        const int l     = chunk & 63;
        const int kstep = (chunk >> 6) & 7;
        const int mt2   = chunk >> 9;
        const int m     = mt2 * 32 + (l & 31);
        const int k0    = kstep * 16 + ((l >> 5) & 1) * 8;
        const float4 a = *(const float4*)&W1_[m * 128 + k0];
        const float4 b = *(const float4*)&W1_[m * 128 + k0 + 4];
        half8v hh;
        hh[0] = (_Float16)a.x; hh[1] = (_Float16)a.y;
        hh[2] = (_Float16)a.z; hh[3] = (_Float16)a.w;
        hh[4] = (_Float16)b.x; hh[5] = (_Float16)b.y;
        hh[6] = (_Float16)b.z; hh[7] = (_Float16)b.w;
        *(half8v*)&fragW1[(size_t)chunk * 8] = hh;
    }
    for (int i = tid; i < 128; i += BLOCKT) { sB1[i] = b1_[i]; sW2[i] = W2_[i]; }
    const float b2v = b2_[0];

    __syncthreads();   // the only barrier

    const int gw = blockIdx.x * 4 + w;

    #pragma unroll 1
    for (int it = 0; it < WITERS; ++it) {
        const int rbase = (gw * WITERS + it) * WROWS;

        // ---------- stage 1: features (lanes 0..31, lane = row) ----------
        float ex = 0.f, ez1 = 0.f, ez2 = 0.f, eD1 = 0.f, eD2 = 0.f, elb = 0.f, eub = 0.f;
        if (lane < WROWS) {
            const int r = rbase + lane;
            const float x   = x_[r];
            const float x1  = x1_[r];
            const float x2  = x2_[r];
            float       z1  = z1_[r];
            float       z2  = z2_[r];
            const float x1E = x1E_[r];
            const float x2E = x2E_[r];
            const float z1E = z1E_[r];
            const float z2E = z2E_[r];
            const float mu  = muB_[r >> 11];

            z1 = ((z1 + mu) <= 0.0f) ? 0.0f : z1;
            z2 = ((z2 + mu) <= 0.0f) ? 0.0f : z2;
            float invD1 = (z1 + mu) * fast_rcp(x1 + mu + 1e-12f);
            float invD2 = (z2 + mu) * fast_rcp(x2 + mu + 1e-12f);
            invD1 = fminf(fmaxf(invD1, 0.0f), 100.0f);
            invD2 = fminf(fmaxf(invD2, 0.0f), 100.0f);

            const float f[15] = { x, x1, x2, z1, z2, x, z1, z2,
                                  x1E, x2E, z1E, z2E, mu, invD1, invD2 };
            half8v f0, f1;
            #pragma unroll
            for (int k = 0; k < 8; ++k) f0[k] = (_Float16)f[k];
            #pragma unroll
            for (int k = 0; k < 7; ++k) f1[k] = (_Float16)f[8 + k];
            f1[7] = (_Float16)1.0f;                 // bias activator (k=15)
            *(half8v*)&sFeat[w][lane * 16]     = f0;
            *(half8v*)&sFeat[w][lane * 16 + 8] = f1;

            ex = x; ez1 = z1; ez2 = z2; eD1 = invD1; eD2 = invD2;
            elb = lb_[r]; eub = ub_[r];
        }
        // same-wave LDS write->read is in-order; no barrier (wave-private region)

        // feat B-frag: B[k=hk*8+j][n=row m32] — 1KB contiguous, 1 b128/lane
        const half8v fB = *(const half8v*)&sFeat[w][m32 * 16 + hk * 8];

        float16v acc[4];
        #pragma unroll
        for (int t = 0; t < 4; ++t) acc[t] = (float16v){};

        // ---------- gate tiles (32 neurons each) + head ksteps ----------
        #pragma unroll
        for (int nt = 0; nt < 4; ++nt) {
            const half8v Ai = *(const half8v*)&fragWih[((0 * 4 + nt) * 64 + lane) * 8];
            const half8v Ag = *(const half8v*)&fragWih[((1 * 4 + nt) * 64 + lane) * 8];
            const half8v Ao = *(const half8v*)&fragWih[((2 * 4 + nt) * 64 + lane) * 8];
            const float16v z16 = (float16v){};
            float16v Di = __builtin_amdgcn_mfma_f32_32x32x16_f16(Ai, fB, z16, 0, 0, 0);
            float16v Dg = __builtin_amdgcn_mfma_f32_32x32x16_f16(Ag, fB, z16, 0, 0, 0);
            float16v Do = __builtin_amdgcn_mfma_f32_32x32x16_f16(Ao, fB, z16, 0, 0, 0);

            // activations: reg r -> neuron_loc = (r&3) + 8*(r>>2) + 4*hk (row m32)
            H4 run[4];
            #pragma unroll
            for (int t = 0; t < 4; ++t) {
                #pragma unroll
                for (int d = 0; d < 4; ++d) {
                    const int rg = t * 4 + d;
                    const float cv = sigm(Di[rg]) * tanh_f(Dg[rg]);
                    run[t].h[d] = (_Float16)(sigm(Do[rg]) * tanh_c(cv));
                }
            }

            // head B-frags via half-wave b64 swap: lane needs neurons
            // 16*kp + 8*hk + (0..7) of its row; owns runs 8t+4*hk+(0..3).
            #pragma unroll
            for (int kp = 0; kp < 2; ++kp) {
                const int t0 = 2 * kp, t1 = 2 * kp + 1;
                const unsigned int s0 = hk ? run[t0].u[0] : run[t1].u[0]; // send run 2kp+(1-hk)
                const unsigned int s1 = hk ? run[t0].u[1] : run[t1].u[1];
                const unsigned int k0 = hk ? run[t1].u[0] : run[t0].u[0]; // keep run 2kp+hk
                const unsigned int k1 = hk ? run[t1].u[1] : run[t0].u[1];
                const unsigned int r0 = (unsigned int)__shfl_xor((int)s0, 32, 64);
                const unsigned int r1 = (unsigned int)__shfl_xor((int)s1, 32, 64);
                B8 bf;
                bf.u[0] = hk ? r0 : k0;   // j=0..3
                bf.u[1] = hk ? r1 : k1;
                bf.u[2] = hk ? k0 : r0;   // j=4..7
                bf.u[3] = hk ? k1 : r1;
                const int kstep = nt * 2 + kp;
                #pragma unroll
                for (int mt2 = 0; mt2 < 4; ++mt2) {
                    const half8v A1 = *(const half8v*)&fragW1[((mt2 * 8 + kstep) * 64 + lane) * 8];
                    acc[mt2] = __builtin_amdgcn_mfma_f32_32x32x16_f16(A1, bf.h, acc[mt2], 0, 0, 0);
                }
            }
        }

        // ---------- epilogue: relu(+b1)*W2 over 64 neurons/lane, 1 shuffle ----------
        float v = 0.f;
        #pragma unroll
        for (int mt2 = 0; mt2 < 4; ++mt2) {
            #pragma unroll
            for (int rq = 0; rq < 4; ++rq) {
                // neuron2 = mt2*32 + 8*rq + 4*hk + d  (d = 0..3)
                const float4 b1q = *(const float4*)&sB1[mt2 * 32 + rq * 8 + hk * 4];
                const float4 w2q = *(const float4*)&sW2[mt2 * 32 + rq * 8 + hk * 4];
                v = __builtin_fmaf(fmaxf(acc[mt2][rq * 4 + 0] + b1q.x, 0.f), w2q.x, v);
                v = __builtin_fmaf(fmaxf(acc[mt2][rq * 4 + 1] + b1q.y, 0.f), w2q.y, v);
                v = __builtin_fmaf(fmaxf(acc[mt2][rq * 4 + 2] + b1q.z, 0.f), w2q.z, v);
                v = __builtin_fmaf(fmaxf(acc[mt2][rq * 4 + 3] + b1q.w, 0.f), w2q.w, v);
            }
        }
        v += __shfl_xor(v, 32, 64);   // combine the two hk-halves (full 128-neuron sum)

        if (lane < WROWS) {
            const int   r     = rbase + lane;
            const int   b     = r >> 11;
            const int   n     = r & (N_SZ - 1);
            const float p     = v + b2v;
            const float pxx   = fabsf(p) * ex;
            const float x_new = ex - pxx;
            float* ob = out_ + (size_t)b * (5 * N_SZ) + n;
            ob[0 * N_SZ] = x_new;
            ob[1 * N_SZ] = x_new - elb;               // has_lb all-true
            ob[2 * N_SZ] = eub - x_new;               // has_ub all-true
            ob[3 * N_SZ] = ez1 - eD1 * (ez1 - pxx);
            ob[4 * N_SZ] = ez2 - eD2 * (ez2 + pxx);
        }
    }
}

extern "C" void kernel_launch(void* const* d_in, const int* in_sizes, int n_in,
                              void* d_out, int out_size, void* d_ws, size_t ws_size,
                              hipStream_t stream) {
    (void)in_sizes; (void)n_in; (void)out_size; (void)d_ws; (void)ws_size;
    const float* x_   = (const float*)d_in[0];
    const float* x1_  = (const float*)d_in[1];
    const float* x2_  = (const float*)d_in[2];
    const float* z1_  = (const float*)d_in[3];
    const float* z2_  = (const float*)d_in[4];
    const float* x1E_ = (const float*)d_in[5];
    const float* x2E_ = (const float*)d_in[6];
    const float* z1E_ = (const float*)d_in[7];
    const float* z2E_ = (const float*)d_in[8];
    const float* muB_ = (const float*)d_in[9];
    const float* lb_  = (const float*)d_in[10];
    const float* ub_  = (const float*)d_in[11];
    const float* Wih_ = (const float*)d_in[14];
    const float* bih_ = (const float*)d_in[16];
    const float* bhh_ = (const float*)d_in[17];
    const float* W1_  = (const float*)d_in[18];
    const float* b1_  = (const float*)d_in[19];
    const float* W2_  = (const float*)d_in[20];
    const float* b2_  = (const float*)d_in[21];
    float* out_ = (float*)d_out;

    ps_lstm_r32<<<NBLK, BLOCKT, 0, stream>>>(
        x_, x1_, x2_, z1_, z2_, x1E_, x2E_, z1E_, z2E_, muB_, lb_, ub_,
        Wih_, bih_, bhh_, W1_, b1_, W2_, b2_, out_);
}

// Round 7
// 180.940 us; speedup vs baseline: 1.0986x; 1.0986x over previous
//
#include <hip/hip_runtime.h>

// PS_L20_LSTM — round-4 skeleton + transposed gate GEMM.
// Gate GEMM D = Wih·feat^T (weights = A, K=32: 15 feats + bias col @k=15 + zeros).
// D reg-rows = 4 contiguous neurons -> packed ds_write_b64 into the per-wave
// 32-neuron h slice. Head GEMM (round-4 form): A = h rows from slice, B = W1.
// Wave-independent 32-row tiles, one staging barrier total. No unions, no
// indexed local arrays (spill-safe: round-5/6 scratch pathology).

typedef _Float16 half8v  __attribute__((ext_vector_type(8)));
typedef _Float16 half4v  __attribute__((ext_vector_type(4)));
typedef float    float4v __attribute__((ext_vector_type(4)));

#define N_SZ   2048
#define ROWS   262144
#define BLOCKT 256
#define NBLK   512          // 512 blk x 4 waves x 4 iters x 32 rows = 262144
#define WITERS 4
#define WROWS  32

#define HS 136   // sW1T row stride (f16): 272 B, 16B-aligned
#define SS 40    // sHs row stride (f16): 80 B, 16B-aligned

__device__ __forceinline__ float fast_rcp(float x) { return __builtin_amdgcn_rcpf(x); }
__device__ __forceinline__ float sigm(float x)  { return fast_rcp(1.0f + __expf(-x)); }
__device__ __forceinline__ float tanh_f(float x){ return 1.0f - 2.0f * fast_rcp(1.0f + __expf(2.0f * x)); }
// |y| <= 1: odd deg-7 minimax, err ~1e-4, full-rate FMA pipe
__device__ __forceinline__ float tanh_c(float y) {
    const float t = y * y;
    return y * __builtin_fmaf(t, __builtin_fmaf(t, __builtin_fmaf(t,
            -0.02714f, 0.12052f), -0.33157f), 0.99986f);
}

__global__ __launch_bounds__(BLOCKT, 2)
void ps_lstm_tg(const float* __restrict__ x_,
                const float* __restrict__ x1_,
                const float* __restrict__ x2_,
                const float* __restrict__ z1_,
                const float* __restrict__ z2_,
                const float* __restrict__ x1E_,
                const float* __restrict__ x2E_,
                const float* __restrict__ z1E_,
                const float* __restrict__ z2E_,
                const float* __restrict__ muB_,
                const float* __restrict__ lb_,
                const float* __restrict__ ub_,
                const float* __restrict__ Wih_,   // [512][15]
                const float* __restrict__ bih_,   // [512]
                const float* __restrict__ bhh_,   // [512]
                const float* __restrict__ W1_,    // [128][128]
                const float* __restrict__ b1_,    // [128]
                const float* __restrict__ W2_,    // [128]
                const float* __restrict__ b2_,    // [1]
                float* __restrict__ out_)         // [128][5*2048]
{
    // Gate A-frags in frag-order: [gate][mt][lane][8], lane-contiguous 16B -> conflict-free.
    // A[m=lane&15][k=(lane>>4)*8+j]; k=15 = fused bias, k>=16 staged zero.
    __shared__ __align__(16) _Float16 fragWih[3 * 8 * 64 * 8];   // 24.6 KB
    __shared__ __align__(16) _Float16 sW1T [128 * HS];           // 34.8 KB [n][k]
    __shared__ __align__(16) _Float16 sFeat[4][WROWS * 16];      // 4 KB per-wave [row][k<16]
    __shared__ __align__(16) _Float16 sHs  [4][WROWS * SS];      // 10.2 KB per-wave slice
    __shared__ float sP[4][WROWS];                               // 0.5 KB

    const int tid  = threadIdx.x;
    const int lane = tid & 63;
    const int w    = tid >> 6;
    const int c    = lane & 15;    // MFMA lane index
    const int q    = lane >> 4;    // quad

    // ---------- one-time staging ----------
    // gate frags: 1536 chunks of 16 B
    for (int ch = tid; ch < 3 * 8 * 64; ch += BLOCKT) {
        const int g   = ch >> 9;            // 0:i 1:g 2:o
        const int rem = ch & 511;
        const int mt  = rem >> 6;
        const int l   = rem & 63;
        const int m   = mt * 16 + (l & 15);
        const int qq  = l >> 4;
        const int grow = (g == 0 ? m : (g == 1 ? 256 + m : 384 + m));  // skip dead f-gate
        half8v hh;
        #pragma unroll
        for (int j = 0; j < 8; ++j) {
            const int k = qq * 8 + j;
            float v = 0.0f;
            if (k < 15)       v = Wih_[grow * 15 + k];
            else if (k == 15) v = bih_[grow] + bhh_[grow];   // bias column
            hh[j] = (_Float16)v;
        }
        *(half8v*)&fragWih[(size_t)ch * 8] = hh;
    }
    {
        const int n  = tid >> 1;
        const int hf = tid & 1;
        const float4* src = (const float4*)(W1_ + n * 128 + hf * 64);
        #pragma unroll
        for (int v = 0; v < 16; v += 2) {
            const float4 a  = src[v];
            const float4 bq = src[v + 1];
            half8v hh;
            hh[0] = (_Float16)a.x;  hh[1] = (_Float16)a.y;
            hh[2] = (_Float16)a.z;  hh[3] = (_Float16)a.w;
            hh[4] = (_Float16)bq.x; hh[5] = (_Float16)bq.y;
            hh[6] = (_Float16)bq.z; hh[7] = (_Float16)bq.w;
            *(half8v*)&sW1T[n * HS + hf * 64 + v * 4] = hh;
        }
    }

    // per-lane head bias/weight registers (neuron set fixed: nt*16+c)
    float b1r[8], w2r[8];
    #pragma unroll
    for (int nt = 0; nt < 8; ++nt) {
        b1r[nt] = b1_[nt * 16 + c];
        w2r[nt] = W2_[nt * 16 + c];
    }
    const float b2v = b2_[0];

    __syncthreads();   // the only barrier

    const int gw = blockIdx.x * 4 + w;

    #pragma unroll 1
    for (int it = 0; it < WITERS; ++it) {
        const int rbase = (gw * WITERS + it) * WROWS;

        // ---------- stage 1: features (lanes 0..31, lane = row) ----------
        float ex = 0.f, ez1 = 0.f, ez2 = 0.f, eD1 = 0.f, eD2 = 0.f, elb = 0.f, eub = 0.f;
        if (lane < WROWS) {
            const int r = rbase + lane;
            const float x   = x_[r];
            const float x1  = x1_[r];
            const float x2  = x2_[r];
            float       z1  = z1_[r];
            float       z2  = z2_[r];
            const float x1E = x1E_[r];
            const float x2E = x2E_[r];
            const float z1E = z1E_[r];
            const float z2E = z2E_[r];
            const float mu  = muB_[r >> 11];

            z1 = ((z1 + mu) <= 0.0f) ? 0.0f : z1;
            z2 = ((z2 + mu) <= 0.0f) ? 0.0f : z2;
            float invD1 = (z1 + mu) * fast_rcp(x1 + mu + 1e-12f);
            float invD2 = (z2 + mu) * fast_rcp(x2 + mu + 1e-12f);
            invD1 = fminf(fmaxf(invD1, 0.0f), 100.0f);
            invD2 = fminf(fmaxf(invD2, 0.0f), 100.0f);

            const float f[15] = { x, x1, x2, z1, z2, x, z1, z2,
                                  x1E, x2E, z1E, z2E, mu, invD1, invD2 };
            half8v f0, f1;
            #pragma unroll
            for (int k = 0; k < 8; ++k) f0[k] = (_Float16)f[k];
            #pragma unroll
            for (int k = 0; k < 7; ++k) f1[k] = (_Float16)f[8 + k];
            f1[7] = (_Float16)1.0f;                 // bias activator (k=15)
            *(half8v*)&sFeat[w][lane * 16]     = f0;
            *(half8v*)&sFeat[w][lane * 16 + 8] = f1;

            ex = x; ez1 = z1; ez2 = z2; eD1 = invD1; eD2 = invD2;
            elb = lb_[r]; eub = ub_[r];
        }
        // wave-private LDS; same-wave DS ordering -> no barrier

        // feat B-frags (loop-invariant): B[k=q*8+j][n=row ntr*16+c]; k>=16 zero
        half8v z8;
        #pragma unroll
        for (int k = 0; k < 8; ++k) z8[k] = (_Float16)0.f;
        half8v fB0 = (q < 2) ? *(const half8v*)&sFeat[w][(0 * 16 + c) * 16 + q * 8] : z8;
        half8v fB1 = (q < 2) ? *(const half8v*)&sFeat[w][(1 * 16 + c) * 16 + q * 8] : z8;

        float4v acc[8][2];
        #pragma unroll
        for (int nt = 0; nt < 8; ++nt)
            #pragma unroll
            for (int m = 0; m < 2; ++m)
                acc[nt][m] = (float4v){0.f, 0.f, 0.f, 0.f};

        #pragma unroll
        for (int kk = 0; kk < 4; ++kk) {
            // ----- transposed gate GEMM: produce slice neurons kk*32 .. kk*32+31 -----
            #pragma unroll
            for (int mtl = 0; mtl < 2; ++mtl) {
                const int mt = kk * 2 + mtl;
                const half8v Ai = *(const half8v*)&fragWih[((0 * 8 + mt) * 64 + lane) * 8];
                const half8v Ag = *(const half8v*)&fragWih[((1 * 8 + mt) * 64 + lane) * 8];
                const half8v Ao = *(const half8v*)&fragWih[((2 * 8 + mt) * 64 + lane) * 8];
                #pragma unroll
                for (int ntr = 0; ntr < 2; ++ntr) {
                    const half8v fB = ntr ? fB1 : fB0;
                    const float4v zc = {0.f, 0.f, 0.f, 0.f};
                    float4v di = __builtin_amdgcn_mfma_f32_16x16x32_f16(Ai, fB, zc, 0, 0, 0);
                    float4v dg = __builtin_amdgcn_mfma_f32_16x16x32_f16(Ag, fB, zc, 0, 0, 0);
                    float4v dv = __builtin_amdgcn_mfma_f32_16x16x32_f16(Ao, fB, zc, 0, 0, 0);
                    // D: col c = row (within ntr tile), reg-rows = neurons q*4+j
                    half4v h4;
                    #pragma unroll
                    for (int j = 0; j < 4; ++j) {
                        const float cv = sigm(di[j]) * tanh_f(dg[j]);
                        h4[j] = (_Float16)(sigm(dv[j]) * tanh_c(cv));
                    }
                    *(half4v*)&sHs[w][(ntr * 16 + c) * SS + mtl * 16 + q * 4] = h4;
                }
            }
            // ----- head GEMM k-step (round-4 form): A = h rows, B = W1 -----
            half8v hA0 = *(const half8v*)&sHs[w][(0 * 16 + c) * SS + q * 8];
            half8v hA1 = *(const half8v*)&sHs[w][(1 * 16 + c) * SS + q * 8];
            #pragma unroll
            for (int nt = 0; nt < 8; ++nt) {
                const half8v Bh = *(const half8v*)&sW1T[(nt * 16 + c) * HS + kk * 32 + q * 8];
                acc[nt][0] = __builtin_amdgcn_mfma_f32_16x16x32_f16(hA0, Bh, acc[nt][0], 0, 0, 0);
                acc[nt][1] = __builtin_amdgcn_mfma_f32_16x16x32_f16(hA1, Bh, acc[nt][1], 0, 0, 0);
            }
        }

        // ---------- epilogue (round-4 form): relu(+b1)*W2, lane-c reduce -> p ----------
        float p00 = 0.f, p01 = 0.f, p02 = 0.f, p03 = 0.f;
        float p10 = 0.f, p11 = 0.f, p12 = 0.f, p13 = 0.f;
        #pragma unroll
        for (int nt = 0; nt < 8; ++nt) {
            const float bb = b1r[nt];
            const float ww = w2r[nt];
            p00 = __builtin_fmaf(fmaxf(acc[nt][0][0] + bb, 0.f), ww, p00);
            p01 = __builtin_fmaf(fmaxf(acc[nt][0][1] + bb, 0.f), ww, p01);
            p02 = __builtin_fmaf(fmaxf(acc[nt][0][2] + bb, 0.f), ww, p02);
            p03 = __builtin_fmaf(fmaxf(acc[nt][0][3] + bb, 0.f), ww, p03);
            p10 = __builtin_fmaf(fmaxf(acc[nt][1][0] + bb, 0.f), ww, p10);
            p11 = __builtin_fmaf(fmaxf(acc[nt][1][1] + bb, 0.f), ww, p11);
            p12 = __builtin_fmaf(fmaxf(acc[nt][1][2] + bb, 0.f), ww, p12);
            p13 = __builtin_fmaf(fmaxf(acc[nt][1][3] + bb, 0.f), ww, p13);
        }
        // reduce over the 16 c-lanes (neuron dimension)
        #pragma unroll
        for (int s = 1; s <= 8; s <<= 1) {
            p00 += __shfl_xor(p00, s, 64);  p01 += __shfl_xor(p01, s, 64);
            p02 += __shfl_xor(p02, s, 64);  p03 += __shfl_xor(p03, s, 64);
            p10 += __shfl_xor(p10, s, 64);  p11 += __shfl_xor(p11, s, 64);
            p12 += __shfl_xor(p12, s, 64);  p13 += __shfl_xor(p13, s, 64);
        }
        if (c == 0) {
            // row (m*16 + q*4 + j) of this wave's 32-row tile
            sP[w][0 * 16 + q * 4 + 0] = p00;
            sP[w][0 * 16 + q * 4 + 1] = p01;
            sP[w][0 * 16 + q * 4 + 2] = p02;
            sP[w][0 * 16 + q * 4 + 3] = p03;
            sP[w][1 * 16 + q * 4 + 0] = p10;
            sP[w][1 * 16 + q * 4 + 1] = p11;
            sP[w][1 * 16 + q * 4 + 2] = p12;
            sP[w][1 * 16 + q * 4 + 3] = p13;
        }
        if (lane < WROWS) {
            const int   r     = rbase + lane;
            const int   b     = r >> 11;
            const int   n     = r & (N_SZ - 1);
            const float p     = sP[w][lane] + b2v;
            const float pxx   = fabsf(p) * ex;
            const float x_new = ex - pxx;
            float* ob = out_ + (size_t)b * (5 * N_SZ) + n;
            ob[0 * N_SZ] = x_new;
            ob[1 * N_SZ] = x_new - elb;               // has_lb all-true
            ob[2 * N_SZ] = eub - x_new;               // has_ub all-true
            ob[3 * N_SZ] = ez1 - eD1 * (ez1 - pxx);
            ob[4 * N_SZ] = ez2 - eD2 * (ez2 + pxx);
        }
    }
}

extern "C" void kernel_launch(void* const* d_in, const int* in_sizes, int n_in,
                              void* d_out, int out_size, void* d_ws, size_t ws_size,
                              hipStream_t stream) {
    (void)in_sizes; (void)n_in; (void)out_size; (void)d_ws; (void)ws_size;
    const float* x_   = (const float*)d_in[0];
    const float* x1_  = (const float*)d_in[1];
    const float* x2_  = (const float*)d_in[2];
    const float* z1_  = (const float*)d_in[3];
    const float* z2_  = (const float*)d_in[4];
    const float* x1E_ = (const float*)d_in[5];
    const float* x2E_ = (const float*)d_in[6];
    const float* z1E_ = (const float*)d_in[7];
    const float* z2E_ = (const float*)d_in[8];
    const float* muB_ = (const float*)d_in[9];
    const float* lb_  = (const float*)d_in[10];
    const float* ub_  = (const float*)d_in[11];
    const float* Wih_ = (const float*)d_in[14];
    const float* bih_ = (const float*)d_in[16];
    const float* bhh_ = (const float*)d_in[17];
    const float* W1_  = (const float*)d_in[18];
    const float* b1_  = (const float*)d_in[19];
    const float* W2_  = (const float*)d_in[20];
    const float* b2_  = (const float*)d_in[21];
    float* out_ = (float*)d_out;

    ps_lstm_tg<<<NBLK, BLOCKT, 0, stream>>>(
        x_, x1_, x2_, z1_, z2_, x1E_, x2E_, z1E_, z2E_, muB_, lb_, ub_,
        Wih_, bih_, bhh_, W1_, b1_, W2_, b2_, out_);
}